// Round 3
// baseline (448.403 us; speedup 1.0000x reference)
//
#include <hip/hip_runtime.h>

typedef unsigned short u16;
typedef __attribute__((ext_vector_type(8))) short bf16x8;
typedef __attribute__((ext_vector_type(4))) short bf16x4;
typedef __attribute__((ext_vector_type(4))) float f32x4;

#define NB 2
#define SEQ 2048
#define HID 1024
#define NHEAD 16
#define HD 64
#define MROWS (NB * SEQ) /* 4096 */

__device__ __forceinline__ u16 f2bf(float f) {
  union { float f; unsigned u; } x; x.f = f;
  unsigned r = x.u + 0x7fffu + ((x.u >> 16) & 1u);
  return (u16)(r >> 16);
}

#define GLOAD_LDS16(g, l)                                                   \
  __builtin_amdgcn_global_load_lds(                                         \
      (const __attribute__((address_space(1))) void*)(g),                   \
      (__attribute__((address_space(3))) void*)(l), 16, 0, 0)

// f32 -> bf16 elementwise, 8 elems/thread. nvec = elems/8 (exact multiple).
__global__ __launch_bounds__(256)
void conv_f32_bf16(const float* __restrict__ src, u16* __restrict__ dst, int nvec)
{
  const int i = blockIdx.x * 256 + threadIdx.x;
  if (i >= nvec) return;
  const float* s = src + (size_t)i * 8;
  f32x4 a = *(const f32x4*)s;
  f32x4 b = *(const f32x4*)(s + 4);
  bf16x8 o;
#pragma unroll
  for (int j = 0; j < 4; ++j) { o[j] = (short)f2bf(a[j]); o[4 + j] = (short)f2bf(b[j]); }
  *(bf16x8*)(dst + (size_t)i * 8) = o;
}

// C[m,n] = (sum_k A[m,k]*W[n,k] + bias[n]) * scale.  A,W bf16; bias f32.
// BM=64 BN=128 BK=32, 4 waves, global_load_lds staging (m97 structure).
// mode 0: bf16 split-head Out[b][h][n][d]
// mode 1: f32 row-major   Out[m][n]
// mode 2: bf16 transposed Out[b][h][d][n]   (for V)
__global__ __launch_bounds__(256)
void gemm_bf16(const u16* __restrict__ A, const u16* __restrict__ W,
               const float* __restrict__ bias, void* __restrict__ Out_,
               float scale, int mode)
{
  __shared__ u16 As[64 * 32];    // 4 KB, linear (required by global_load_lds)
  __shared__ u16 Bs[128 * 32];   // 8 KB
  const int n0 = blockIdx.x * 128;
  const int m0 = blockIdx.y * 64;
  const int t = threadIdx.x;
  const int lane = t & 63, w = t >> 6;
  const int grp = lane >> 4, lr = lane & 15;
  const int wr = (w >> 1) * 32;  // wave M offset (2x2 wave grid, 32x64 each)
  const int wc = (w & 1) * 64;

  f32x4 acc[2][4];
#pragma unroll
  for (int i = 0; i < 2; ++i)
#pragma unroll
    for (int j = 0; j < 4; ++j) acc[i][j] = (f32x4){0.f, 0.f, 0.f, 0.f};

  // staging: lane i covers row (chunkbase + i/4), 8 bf16 at kcol (i%4)*8
  const int sr = lane >> 2, kc = (lane & 3) * 8;
  const u16* ag  = A + (size_t)(m0 + w * 16 + sr) * HID + kc;
  const u16* bg0 = W + (size_t)(n0 + w * 32 + sr) * HID + kc;
  const u16* bg1 = bg0 + (size_t)16 * HID;
  u16* al  = As + w * 16 * 32;   // wave-uniform LDS bases
  u16* bl0 = Bs + w * 32 * 32;
  u16* bl1 = bl0 + 16 * 32;

  for (int k0 = 0; k0 < HID; k0 += 32) {
    GLOAD_LDS16(ag + k0, al);
    GLOAD_LDS16(bg0 + k0, bl0);
    GLOAD_LDS16(bg1 + k0, bl1);
    __syncthreads();               // drains vmcnt -> staged data visible
    bf16x8 af[2], bf[4];
#pragma unroll
    for (int mi = 0; mi < 2; ++mi)
      af[mi] = *(const bf16x8*)&As[(wr + mi * 16 + lr) * 32 + grp * 8];
#pragma unroll
    for (int ni = 0; ni < 4; ++ni)
      bf[ni] = *(const bf16x8*)&Bs[(wc + ni * 16 + lr) * 32 + grp * 8];
#pragma unroll
    for (int mi = 0; mi < 2; ++mi)
#pragma unroll
      for (int ni = 0; ni < 4; ++ni)
        acc[mi][ni] = __builtin_amdgcn_mfma_f32_16x16x32_bf16(
            af[mi], bf[ni], acc[mi][ni], 0, 0, 0);
    __syncthreads();               // protect LDS before next overwrite
  }

#pragma unroll
  for (int mi = 0; mi < 2; ++mi) {
#pragma unroll
    for (int ni = 0; ni < 4; ++ni) {
      const int n = n0 + wc + ni * 16 + lr;
      const float bval = bias[n];
      const int mb = m0 + wr + mi * 16 + grp * 4;  // +r, r=0..3
      if (mode == 1) {
        float* O = (float*)Out_;
#pragma unroll
        for (int r = 0; r < 4; ++r)
          O[(size_t)(mb + r) * HID + n] = (acc[mi][ni][r] + bval) * scale;
      } else if (mode == 0) {
        u16* O = (u16*)Out_;
        const int h = n >> 6, d = n & (HD - 1);
#pragma unroll
        for (int r = 0; r < 4; ++r) {
          const int m = mb + r;
          const int b = m >> 11, nn = m & (SEQ - 1);
          O[((size_t)(b * NHEAD + h) * SEQ + nn) * HD + d] =
              f2bf((acc[mi][ni][r] + bval) * scale);
        }
      } else {  // mode 2: transposed V  Out[b][h][d][n]
        u16* O = (u16*)Out_;
        const int h = n >> 6, d = n & (HD - 1);
        const int b = mb >> 11, nn = mb & (SEQ - 1);
        bf16x4 pk;
#pragma unroll
        for (int r = 0; r < 4; ++r)
          pk[r] = (short)f2bf((acc[mi][ni][r] + bval) * scale);
        *(bf16x4*)&O[((size_t)(b * NHEAD + h) * HD + d) * SEQ + nn] = pk;
      }
    }
  }
}

// Causal flash attention, KVBLK=64. Q pre-scaled by 0.125*log2(e).
// Q,K: [bh][n][64] bf16;  Vt: [bh][64][n] bf16 (transposed).
// O: [b][n][HID] bf16. 4 waves/block, 16 q-rows/wave. Swapped QK^T:
// S^T frag == PV A-frag layout, softmax fully in-register.
__global__ __launch_bounds__(256)
void attn_fwd(const u16* __restrict__ Q, const u16* __restrict__ K,
              const u16* __restrict__ Vt, u16* __restrict__ O)
{
  const int bh = blockIdx.y;
  const int t = threadIdx.x;
  const int w = t >> 6, lane = t & 63;
  const int grp = lane >> 4, lr = lane & 15;
  const int qt = gridDim.x - 1 - blockIdx.x;   // heavy blocks dispatch first
  const int q0 = qt * 64 + w * 16;
  const size_t base = (size_t)bh * SEQ * HD;   // K (row-major) & Q base
  const float NEGINF = -__builtin_inff();

  const bf16x8 aq0 = *(const bf16x8*)&Q[base + (size_t)(q0 + lr) * HD + grp * 8];
  const bf16x8 aq1 = *(const bf16x8*)&Q[base + (size_t)(q0 + lr) * HD + grp * 8 + 32];

  float m_i = NEGINF, l_i = 0.f;
  f32x4 o_acc[4];
#pragma unroll
  for (int c = 0; c < 4; ++c) o_acc[c] = (f32x4){0.f, 0.f, 0.f, 0.f};

  const int qg = q0 + lr;          // q row whose stats this lane owns
  const int lt = (q0 + 15) >> 6;   // the single masked (diagonal) tile

  for (int it = 0; it <= lt; ++it) {
    const int j0 = it << 6;
    f32x4 sv[4];
#pragma unroll
    for (int st = 0; st < 4; ++st) {
      const u16* kp = &K[base + (size_t)(j0 + st * 16 + lr) * HD + grp * 8];
      bf16x8 k0 = *(const bf16x8*)kp;
      bf16x8 k1 = *(const bf16x8*)(kp + 32);
      f32x4 s = (f32x4){0.f, 0.f, 0.f, 0.f};
      s = __builtin_amdgcn_mfma_f32_16x16x32_bf16(k0, aq0, s, 0, 0, 0);
      s = __builtin_amdgcn_mfma_f32_16x16x32_bf16(k1, aq1, s, 0, 0, 0);
      sv[st] = s;
    }
    if (it == lt) {  // wave-uniform branch: apply causal mask on diagonal tile
#pragma unroll
      for (int st = 0; st < 4; ++st)
#pragma unroll
        for (int r = 0; r < 4; ++r)
          if (j0 + st * 16 + grp * 4 + r > qg) sv[st][r] = NEGINF;
    }
    // softmax over 16 kv (per q=lr), stats replicated across grp after xors
    float tm = NEGINF;
#pragma unroll
    for (int st = 0; st < 4; ++st)
      tm = fmaxf(tm, fmaxf(fmaxf(sv[st][0], sv[st][1]), fmaxf(sv[st][2], sv[st][3])));
    tm = fmaxf(tm, __shfl_xor(tm, 16));
    tm = fmaxf(tm, __shfl_xor(tm, 32));
    const float m_new = fmaxf(m_i, tm);
    float rs = 0.f;
#pragma unroll
    for (int st = 0; st < 4; ++st)
#pragma unroll
      for (int r = 0; r < 4; ++r) {
        sv[st][r] = exp2f(sv[st][r] - m_new);
        rs += sv[st][r];
      }
    rs += __shfl_xor(rs, 16);
    rs += __shfl_xor(rs, 32);
    const float alpha = exp2f(m_i - m_new);  // first tile: exp2(-inf)=0
    l_i = l_i * alpha + rs;
    m_i = m_new;
    bf16x4 pa[4];
#pragma unroll
    for (int st = 0; st < 4; ++st)
#pragma unroll
      for (int r = 0; r < 4; ++r) pa[st][r] = (short)f2bf(sv[st][r]);
    // O rows live at q = grp*4+r; fetch their alpha from the stats lane
    float af4[4];
#pragma unroll
    for (int r = 0; r < 4; ++r) af4[r] = __shfl(alpha, (lane & 48) + grp * 4 + r);
#pragma unroll
    for (int c = 0; c < 4; ++c)
#pragma unroll
      for (int r = 0; r < 4; ++r) o_acc[c][r] *= af4[r];
    // PV: B-frag lane holds V[kv = j0+st*16+grp*4+i][d = c*16+lr] -> from Vt
    // contiguous in i: vectorized 8B loads
    const size_t vbase = base + (size_t)lr * SEQ + j0 + grp * 4;
#pragma unroll
    for (int st = 0; st < 4; ++st) {
#pragma unroll
      for (int c = 0; c < 4; ++c) {
        bf16x4 bv = *(const bf16x4*)&Vt[vbase + (size_t)c * 16 * SEQ + st * 16];
        o_acc[c] = __builtin_amdgcn_mfma_f32_16x16x16bf16_1k(pa[st], bv, o_acc[c], 0, 0, 0);
      }
    }
  }

  const int b = bh >> 4, h = bh & (NHEAD - 1);
#pragma unroll
  for (int r = 0; r < 4; ++r) {
    const float li = __shfl(l_i, (lane & 48) + grp * 4 + r);
    const float inv = 1.f / li;
    const int n = q0 + grp * 4 + r;
#pragma unroll
    for (int c = 0; c < 4; ++c)
      O[(size_t)(b * SEQ + n) * HID + h * HD + c * 16 + lr] =
          f2bf(o_acc[c][r] * inv);
  }
}

extern "C" void kernel_launch(void* const* d_in, const int* in_sizes, int n_in,
                              void* d_out, int out_size, void* d_ws, size_t ws_size,
                              hipStream_t stream) {
  const float* q  = (const float*)d_in[0];
  const float* k  = (const float*)d_in[1];
  const float* v  = (const float*)d_in[2];
  /* d_in[3] = mask: tril by construction -> causal handled structurally */
  const float* Wq = (const float*)d_in[4];
  const float* bq = (const float*)d_in[5];
  const float* Wk = (const float*)d_in[6];
  const float* bk = (const float*)d_in[7];
  const float* Wv = (const float*)d_in[8];
  const float* bv = (const float*)d_in[9];
  const float* Wp = (const float*)d_in[10];
  const float* bp = (const float*)d_in[11];

  // ws layout (40 MiB): cb (conv buffer, later AO) | Wq..Wp bf16 | Qh | Kh | Vt
  char* ws = (char*)d_ws;
  u16* cb  = (u16*)(ws);                          // 8 MiB
  u16* Wqb = (u16*)(ws + ( 8u << 20));            // 2 MiB each
  u16* Wkb = (u16*)(ws + (10u << 20));
  u16* Wvb = (u16*)(ws + (12u << 20));
  u16* Wpb = (u16*)(ws + (14u << 20));
  u16* Qh  = (u16*)(ws + (16u << 20));            // 8 MiB each
  u16* Kh  = (u16*)(ws + (24u << 20));
  u16* Vt  = (u16*)(ws + (32u << 20));
  u16* AO  = cb;                                  // alias: cb free after V-gemm

  const int NV_A = MROWS * HID / 8;   // 524288 -> 2048 blocks
  const int NV_W = HID * HID / 8;     // 131072 -> 512 blocks
  const dim3 gg(HID / 128, MROWS / 64);  // (8, 64) = 512 blocks
  const float qscale = 0.125f * 1.4426950408889634f;  // 1/sqrt(64) * log2(e)

  conv_f32_bf16<<<NV_W / 256, 256, 0, stream>>>(Wq, Wqb, NV_W);
  conv_f32_bf16<<<NV_W / 256, 256, 0, stream>>>(Wk, Wkb, NV_W);
  conv_f32_bf16<<<NV_W / 256, 256, 0, stream>>>(Wv, Wvb, NV_W);
  conv_f32_bf16<<<NV_W / 256, 256, 0, stream>>>(Wp, Wpb, NV_W);

  conv_f32_bf16<<<NV_A / 256, 256, 0, stream>>>(q, cb, NV_A);
  gemm_bf16<<<gg, 256, 0, stream>>>(cb, Wqb, bq, Qh, qscale, 0);
  conv_f32_bf16<<<NV_A / 256, 256, 0, stream>>>(k, cb, NV_A);
  gemm_bf16<<<gg, 256, 0, stream>>>(cb, Wkb, bk, Kh, 1.0f, 0);
  conv_f32_bf16<<<NV_A / 256, 256, 0, stream>>>(v, cb, NV_A);
  gemm_bf16<<<gg, 256, 0, stream>>>(cb, Wvb, bv, Vt, 1.0f, 2);

  attn_fwd<<<dim3(SEQ / 64, NB * NHEAD), 256, 0, stream>>>(Qh, Kh, Vt, AO);

  gemm_bf16<<<gg, 256, 0, stream>>>(AO, Wpb, bp, d_out, 1.0f, 1);
}

// Round 4
// 216.633 us; speedup vs baseline: 2.0699x; 2.0699x over previous
//
#include <hip/hip_runtime.h>

typedef unsigned short u16;
typedef __attribute__((ext_vector_type(8))) short bf16x8;
typedef __attribute__((ext_vector_type(4))) short bf16x4;
typedef __attribute__((ext_vector_type(4))) float f32x4;

#define NB 2
#define SEQ 2048
#define HID 1024
#define NHEAD 16
#define HD 64
#define MROWS (NB * SEQ) /* 4096 */

__device__ __forceinline__ u16 f2bf(float f) {
  union { float f; unsigned u; } x; x.f = f;
  unsigned r = x.u + 0x7fffu + ((x.u >> 16) & 1u);
  return (u16)(r >> 16);
}

#define GLOAD_LDS16(g, l)                                                   \
  __builtin_amdgcn_global_load_lds(                                         \
      (const __attribute__((address_space(1))) void*)(g),                   \
      (__attribute__((address_space(3))) void*)(l), 16, 0, 0)

// f32 -> bf16 elementwise, 8 elems/thread. nvec = elems/8 (exact multiple).
__global__ __launch_bounds__(256)
void conv_f32_bf16(const float* __restrict__ src, u16* __restrict__ dst, int nvec)
{
  const int i = blockIdx.x * 256 + threadIdx.x;
  if (i >= nvec) return;
  const float* s = src + (size_t)i * 8;
  f32x4 a = *(const f32x4*)s;
  f32x4 b = *(const f32x4*)(s + 4);
  bf16x8 o;
#pragma unroll
  for (int j = 0; j < 4; ++j) { o[j] = (short)f2bf(a[j]); o[4 + j] = (short)f2bf(b[j]); }
  *(bf16x8*)(dst + (size_t)i * 8) = o;
}

// C[m,n] = (sum_k A[m,k]*W[n,k] + bias[n]) * scale.  A,W bf16; bias f32.
// BM=64 BN=128 BK=32, 4 waves, global_load_lds staging (m97 structure).
// mode 0: bf16 split-head Out[b][h][n][d]
// mode 1: f32 row-major   Out[m][n]
// mode 2: bf16 transposed Out[b][h][d][n]   (for V)
__global__ __launch_bounds__(256)
void gemm_bf16(const u16* __restrict__ A, const u16* __restrict__ W,
               const float* __restrict__ bias, void* __restrict__ Out_,
               float scale, int mode)
{
  __shared__ u16 As[64 * 32];    // 4 KB, linear (required by global_load_lds)
  __shared__ u16 Bs[128 * 32];   // 8 KB
  const int n0 = blockIdx.x * 128;
  const int m0 = blockIdx.y * 64;
  const int t = threadIdx.x;
  const int lane = t & 63, w = t >> 6;
  const int grp = lane >> 4, lr = lane & 15;
  const int wr = (w >> 1) * 32;  // wave M offset (2x2 wave grid, 32x64 each)
  const int wc = (w & 1) * 64;

  f32x4 acc[2][4];
#pragma unroll
  for (int i = 0; i < 2; ++i)
#pragma unroll
    for (int j = 0; j < 4; ++j) acc[i][j] = (f32x4){0.f, 0.f, 0.f, 0.f};

  // staging: lane i covers row (chunkbase + i/4), 8 bf16 at kcol (i%4)*8
  const int sr = lane >> 2, kc = (lane & 3) * 8;
  const u16* ag  = A + (size_t)(m0 + w * 16 + sr) * HID + kc;
  const u16* bg0 = W + (size_t)(n0 + w * 32 + sr) * HID + kc;
  const u16* bg1 = bg0 + (size_t)16 * HID;
  u16* al  = As + w * 16 * 32;   // wave-uniform LDS bases
  u16* bl0 = Bs + w * 32 * 32;
  u16* bl1 = bl0 + 16 * 32;

  for (int k0 = 0; k0 < HID; k0 += 32) {
    GLOAD_LDS16(ag + k0, al);
    GLOAD_LDS16(bg0 + k0, bl0);
    GLOAD_LDS16(bg1 + k0, bl1);
    __syncthreads();               // drains vmcnt -> staged data visible
    bf16x8 af[2], bf[4];
#pragma unroll
    for (int mi = 0; mi < 2; ++mi)
      af[mi] = *(const bf16x8*)&As[(wr + mi * 16 + lr) * 32 + grp * 8];
#pragma unroll
    for (int ni = 0; ni < 4; ++ni)
      bf[ni] = *(const bf16x8*)&Bs[(wc + ni * 16 + lr) * 32 + grp * 8];
#pragma unroll
    for (int mi = 0; mi < 2; ++mi)
#pragma unroll
      for (int ni = 0; ni < 4; ++ni)
        acc[mi][ni] = __builtin_amdgcn_mfma_f32_16x16x32_bf16(
            af[mi], bf[ni], acc[mi][ni], 0, 0, 0);
    __syncthreads();               // protect LDS before next overwrite
  }

#pragma unroll
  for (int mi = 0; mi < 2; ++mi) {
#pragma unroll
    for (int ni = 0; ni < 4; ++ni) {
      const int n = n0 + wc + ni * 16 + lr;
      const float bval = bias[n];
      const int mb = m0 + wr + mi * 16 + grp * 4;  // +r, r=0..3
      if (mode == 1) {
        float* O = (float*)Out_;
#pragma unroll
        for (int r = 0; r < 4; ++r)
          O[(size_t)(mb + r) * HID + n] = (acc[mi][ni][r] + bval) * scale;
      } else if (mode == 0) {
        u16* O = (u16*)Out_;
        const int h = n >> 6, d = n & (HD - 1);
#pragma unroll
        for (int r = 0; r < 4; ++r) {
          const int m = mb + r;
          const int b = m >> 11, nn = m & (SEQ - 1);
          O[((size_t)(b * NHEAD + h) * SEQ + nn) * HD + d] =
              f2bf((acc[mi][ni][r] + bval) * scale);
        }
      } else {  // mode 2: transposed V  Out[b][h][d][n]
        u16* O = (u16*)Out_;
        const int h = n >> 6, d = n & (HD - 1);
        const int b = mb >> 11, nn = mb & (SEQ - 1);
        bf16x4 pk;
#pragma unroll
        for (int r = 0; r < 4; ++r)
          pk[r] = (short)f2bf((acc[mi][ni][r] + bval) * scale);
        *(bf16x4*)&O[((size_t)(b * NHEAD + h) * HD + d) * SEQ + nn] = pk;
      }
    }
  }
}

// Causal flash attention, KVBLK=64, LDS-staged K/V, double-buffered 2-phase
// pipeline. Q pre-scaled by 0.125*log2(e). Q,K: [bh][n][64] bf16;
// Vt: [bh][64][n] bf16. O: [b][n][HID] bf16.
// 4 waves/block over 64 q-rows of ONE bh -> all waves share kv tiles.
// LDS tiles [64][64] bf16 (128 B rows) with chunk ^= (row&7) XOR swizzle:
// linear LDS dest + pre-swizzled global source + swizzled reads (rule 21).
__global__ __launch_bounds__(256)
void attn_fwd(const u16* __restrict__ Q, const u16* __restrict__ K,
              const u16* __restrict__ Vt, u16* __restrict__ O)
{
  __shared__ u16 KB[2][4096];   // [buf][64 kv rows][64 d], 8 KB each
  __shared__ u16 VB[2][4096];   // [buf][64 d rows][64 kv], 8 KB each
  const int bh = blockIdx.y;
  const int t = threadIdx.x;
  const int w = t >> 6, lane = t & 63;
  const int grp = lane >> 4, lr = lane & 15;
  const int qt = gridDim.x - 1 - blockIdx.x;   // heavy blocks dispatch first
  const int q0 = qt * 64 + w * 16;
  const size_t base = (size_t)bh * SEQ * HD;   // Q/K row-major base
  const float NEGINF = -__builtin_inff();

  // staging geometry: srow = lane>>3 (8 rows/wave), chunk col ^= srow
  const int srow = lane >> 3;
  const int scol = (lane & 7) ^ srow;
  const u16* kg = K + base + (size_t)(w * 8 + srow) * HD + scol * 8;
  const u16* vg = Vt + base + (size_t)(w * 8 + srow) * SEQ + scol * 8;

  const bf16x8 aq0 = *(const bf16x8*)&Q[base + (size_t)(q0 + lr) * HD + grp * 8];
  const bf16x8 aq1 = *(const bf16x8*)&Q[base + (size_t)(q0 + lr) * HD + grp * 8 + 32];

  float m_i = NEGINF, l_i = 0.f;
  f32x4 o_acc[4];
#pragma unroll
  for (int c = 0; c < 4; ++c) o_acc[c] = (f32x4){0.f, 0.f, 0.f, 0.f};

  const int qg = q0 + lr;   // q row whose stats this lane owns
  const int lt = qt;        // diagonal (masked) tile index; uniform in block

#define STAGE(bi, j0)                                              \
  {                                                                \
    const u16* ks = kg + (size_t)(j0) * HD;                        \
    const u16* vs = vg + (j0);                                     \
    u16* kl = &KB[bi][w * 512];                                    \
    u16* vl = &VB[bi][w * 512];                                    \
    GLOAD_LDS16(ks, kl);                                           \
    GLOAD_LDS16(ks + (size_t)32 * HD, kl + 2048);                  \
    GLOAD_LDS16(vs, vl);                                           \
    GLOAD_LDS16(vs + (size_t)32 * SEQ, vl + 2048);                 \
  }

  STAGE(0, 0);
  asm volatile("s_waitcnt vmcnt(0)" ::: "memory");
  __syncthreads();

  for (int it = 0; it <= lt; ++it) {
    const int bi = it & 1;
    if (it < lt) STAGE(bi ^ 1, (it + 1) << 6);

    // ---- QK^T: S^T[kv][q] (swapped operands) ----
    const int sw = lr & 7;
    f32x4 sv[4];
    __builtin_amdgcn_s_setprio(1);
#pragma unroll
    for (int st = 0; st < 4; ++st) {
      const int ro = (st * 16 + lr) * 64;
      bf16x8 k0 = *(const bf16x8*)&KB[bi][ro + ((grp ^ sw) * 8)];
      bf16x8 k1 = *(const bf16x8*)&KB[bi][ro + (((grp + 4) ^ sw) * 8)];
      f32x4 s = (f32x4){0.f, 0.f, 0.f, 0.f};
      s = __builtin_amdgcn_mfma_f32_16x16x32_bf16(k0, aq0, s, 0, 0, 0);
      s = __builtin_amdgcn_mfma_f32_16x16x32_bf16(k1, aq1, s, 0, 0, 0);
      sv[st] = s;
    }
    __builtin_amdgcn_s_setprio(0);

    // V B-frags (independent of softmax -> latency hides under it)
    bf16x4 bv[4][4];
#pragma unroll
    for (int st = 0; st < 4; ++st)
#pragma unroll
      for (int c = 0; c < 4; ++c)
        bv[st][c] = *(const bf16x4*)&VB[bi][(c * 16 + lr) * 64 +
                        (((st * 2 + (grp >> 1)) ^ sw) * 8) + (grp & 1) * 4];

    if (it == lt) {  // causal mask, diagonal tile only (wave-uniform branch)
      const int j0 = it << 6;
#pragma unroll
      for (int st = 0; st < 4; ++st)
#pragma unroll
        for (int r = 0; r < 4; ++r)
          if (j0 + st * 16 + grp * 4 + r > qg) sv[st][r] = NEGINF;
    }
    // ---- online softmax over 64 kv for q = lr ----
    float tm = NEGINF;
#pragma unroll
    for (int st = 0; st < 4; ++st)
      tm = fmaxf(tm, fmaxf(fmaxf(sv[st][0], sv[st][1]), fmaxf(sv[st][2], sv[st][3])));
    tm = fmaxf(tm, __shfl_xor(tm, 16));
    tm = fmaxf(tm, __shfl_xor(tm, 32));
    const float m_new = fmaxf(m_i, tm);
    float rs = 0.f;
#pragma unroll
    for (int st = 0; st < 4; ++st)
#pragma unroll
      for (int r = 0; r < 4; ++r) {
        sv[st][r] = exp2f(sv[st][r] - m_new);
        rs += sv[st][r];
      }
    rs += __shfl_xor(rs, 16);
    rs += __shfl_xor(rs, 32);
    const float alpha = exp2f(m_i - m_new);  // first tile: exp2(-inf)=0
    l_i = l_i * alpha + rs;
    m_i = m_new;
    bf16x4 pa[4];
#pragma unroll
    for (int st = 0; st < 4; ++st)
#pragma unroll
      for (int r = 0; r < 4; ++r) pa[st][r] = (short)f2bf(sv[st][r]);
    // O rows live at q = grp*4+r; fetch their alpha from the stats lane
    float af4[4];
#pragma unroll
    for (int r = 0; r < 4; ++r) af4[r] = __shfl(alpha, (lane & 48) + grp * 4 + r);
#pragma unroll
    for (int c = 0; c < 4; ++c)
#pragma unroll
      for (int r = 0; r < 4; ++r) o_acc[c][r] *= af4[r];
    // ---- PV ----
    __builtin_amdgcn_s_setprio(1);
#pragma unroll
    for (int st = 0; st < 4; ++st)
#pragma unroll
      for (int c = 0; c < 4; ++c)
        o_acc[c] = __builtin_amdgcn_mfma_f32_16x16x16bf16_1k(pa[st], bv[st][c],
                                                             o_acc[c], 0, 0, 0);
    __builtin_amdgcn_s_setprio(0);

    asm volatile("s_waitcnt vmcnt(0)" ::: "memory");  // next tile staged
    __syncthreads();                                   // + this tile's reads done
  }
#undef STAGE

  const int b = bh >> 4, h = bh & (NHEAD - 1);
#pragma unroll
  for (int r = 0; r < 4; ++r) {
    const float li = __shfl(l_i, (lane & 48) + grp * 4 + r);
    const float inv = 1.f / li;
    const int n = q0 + grp * 4 + r;
#pragma unroll
    for (int c = 0; c < 4; ++c)
      O[(size_t)(b * SEQ + n) * HID + h * HD + c * 16 + lr] =
          f2bf(o_acc[c][r] * inv);
  }
}

extern "C" void kernel_launch(void* const* d_in, const int* in_sizes, int n_in,
                              void* d_out, int out_size, void* d_ws, size_t ws_size,
                              hipStream_t stream) {
  const float* q  = (const float*)d_in[0];
  const float* k  = (const float*)d_in[1];
  const float* v  = (const float*)d_in[2];
  /* d_in[3] = mask: tril by construction -> causal handled structurally */
  const float* Wq = (const float*)d_in[4];
  const float* bq = (const float*)d_in[5];
  const float* Wk = (const float*)d_in[6];
  const float* bk = (const float*)d_in[7];
  const float* Wv = (const float*)d_in[8];
  const float* bv = (const float*)d_in[9];
  const float* Wp = (const float*)d_in[10];
  const float* bp = (const float*)d_in[11];

  // ws layout (40 MiB): cb (conv buffer, later AO) | Wq..Wp bf16 | Qh | Kh | Vt
  char* ws = (char*)d_ws;
  u16* cb  = (u16*)(ws);                          // 8 MiB
  u16* Wqb = (u16*)(ws + ( 8u << 20));            // 2 MiB each
  u16* Wkb = (u16*)(ws + (10u << 20));
  u16* Wvb = (u16*)(ws + (12u << 20));
  u16* Wpb = (u16*)(ws + (14u << 20));
  u16* Qh  = (u16*)(ws + (16u << 20));            // 8 MiB each
  u16* Kh  = (u16*)(ws + (24u << 20));
  u16* Vt  = (u16*)(ws + (32u << 20));
  u16* AO  = cb;                                  // alias: cb free after V-gemm

  const int NV_A = MROWS * HID / 8;   // 524288 -> 2048 blocks
  const int NV_W = HID * HID / 8;     // 131072 -> 512 blocks
  const dim3 gg(HID / 128, MROWS / 64);  // (8, 64) = 512 blocks
  const float qscale = 0.125f * 1.4426950408889634f;  // 1/sqrt(64) * log2(e)

  conv_f32_bf16<<<NV_W / 256, 256, 0, stream>>>(Wq, Wqb, NV_W);
  conv_f32_bf16<<<NV_W / 256, 256, 0, stream>>>(Wk, Wkb, NV_W);
  conv_f32_bf16<<<NV_W / 256, 256, 0, stream>>>(Wv, Wvb, NV_W);
  conv_f32_bf16<<<NV_W / 256, 256, 0, stream>>>(Wp, Wpb, NV_W);

  conv_f32_bf16<<<NV_A / 256, 256, 0, stream>>>(q, cb, NV_A);
  gemm_bf16<<<gg, 256, 0, stream>>>(cb, Wqb, bq, Qh, qscale, 0);
  conv_f32_bf16<<<NV_A / 256, 256, 0, stream>>>(k, cb, NV_A);
  gemm_bf16<<<gg, 256, 0, stream>>>(cb, Wkb, bk, Kh, 1.0f, 0);
  conv_f32_bf16<<<NV_A / 256, 256, 0, stream>>>(v, cb, NV_A);
  gemm_bf16<<<gg, 256, 0, stream>>>(cb, Wvb, bv, Vt, 1.0f, 2);

  attn_fwd<<<dim3(SEQ / 64, NB * NHEAD), 256, 0, stream>>>(Qh, Kh, Vt, AO);

  gemm_bf16<<<gg, 256, 0, stream>>>(AO, Wpb, bp, d_out, 1.0f, 1);
}